// Round 1
// baseline (445.146 us; speedup 1.0000x reference)
//
#include <hip/hip_runtime.h>
#include <hip/hip_bf16.h>
#include <math.h>

#define EE 768
#define HH 4
#define KK 36
#define BSN 2048
#define SPLITK 4

typedef __attribute__((ext_vector_type(8))) short short8;
typedef __attribute__((ext_vector_type(4))) short short4v;
typedef __attribute__((ext_vector_type(4))) float float4v;

__device__ inline short f2bf(float x){
  return __builtin_bit_cast(short, __float2bfloat16(x));
}
__device__ inline float bf2f(short s){
  return __bfloat162float(__builtin_bit_cast(__hip_bfloat16, s));
}
__device__ inline float gelu_tanh(float x){
  // jax.nn.gelu default (approximate=True)
  float t = tanhf(0.79788456080286536f * (x + 0.044715f * x * x * x));
  return 0.5f * x * (1.0f + t);
}

// async global->LDS, 16B per lane. LDS dest is wave-uniform base + lane*16.
__device__ __forceinline__ void gload16(const short* g, short* l){
  __builtin_amdgcn_global_load_lds(
      (const __attribute__((address_space(1))) unsigned int*)g,
      (__attribute__((address_space(3))) unsigned int*)l, 16, 0, 0);
}

// ---------------------------------------------------------------------------
// v[h][e] = g[h][e] * sum_f W1[h][e][f] * W2y[h][f]    (one wave per (h,e))
// also initializes b1p = b1 (first 12 blocks' worth of threads)
// ---------------------------------------------------------------------------
__global__ __launch_bounds__(256) void k_v(const float* __restrict__ W1,
                                           const float* __restrict__ W2y,
                                           const float* __restrict__ g,
                                           const float* __restrict__ b1,
                                           float* __restrict__ v,
                                           float* __restrict__ b1p){
  const int wid  = blockIdx.x * 4 + (threadIdx.x >> 6);
  const int lane = threadIdx.x & 63;
  const int h = wid / EE, e = wid % EE;
  const float* W  = W1 + ((size_t)h * EE + e) * EE;
  const float* wy = W2y + h * EE;
  float acc = 0.f;
  #pragma unroll
  for (int j = 0; j < 12; ++j){
    int f = lane + 64 * j;
    acc += W[f] * wy[f];
  }
  #pragma unroll
  for (int off = 32; off; off >>= 1) acc += __shfl_xor(acc, off);
  if (lane == 0) v[h * EE + e] = g[h * EE + e] * acc;

  int idx = blockIdx.x * 256 + threadIdx.x;
  if (idx < HH * EE) b1p[idx] = b1[idx];
}

// ---------------------------------------------------------------------------
// b1p[h][f] += sum_e beta[h][e] * W1[h][e][f]   (partial e-chunks + atomics)
// grid: 256 blocks = 4 h * 64 e-chunks of 12
// ---------------------------------------------------------------------------
__global__ __launch_bounds__(256) void k_b1p_acc(const float* __restrict__ W1,
                                                 const float* __restrict__ beta,
                                                 float* __restrict__ b1p){
  const int h   = blockIdx.x >> 6;
  const int ec0 = (blockIdx.x & 63) * 12;
  const float* W  = W1 + (size_t)h * EE * EE;
  const float* bt = beta + h * EE;
  const int f = threadIdx.x;
  float a0 = 0.f, a1 = 0.f, a2 = 0.f;
  #pragma unroll
  for (int e = ec0; e < ec0 + 12; ++e){
    float be = bt[e];
    const float* row = W + (size_t)e * EE;
    a0 += be * row[f];
    a1 += be * row[f + 256];
    a2 += be * row[f + 512];
  }
  atomicAdd(&b1p[h * EE + f],       a0);
  atomicAdd(&b1p[h * EE + f + 256], a1);
  atomicAdd(&b1p[h * EE + f + 512], a2);
}

// ---------------------------------------------------------------------------
// W1t[h][f][e] = bf16( g[h][e] * W1[h][e][f] )   (transposed, bf16)
// grid (24 e-tiles, 24 f-tiles, 4 h), 256 threads
// ---------------------------------------------------------------------------
__global__ __launch_bounds__(256) void k_tW1(const float* __restrict__ W1,
                                             const float* __restrict__ g,
                                             short* __restrict__ W1t){
  __shared__ float tile[32][33];
  const int h  = blockIdx.z;
  const int e0 = blockIdx.x * 32, f0 = blockIdx.y * 32;
  const int tx = threadIdx.x & 31, ty = threadIdx.x >> 5;
  const float* W = W1 + (size_t)h * EE * EE;
  #pragma unroll
  for (int i = 0; i < 4; ++i){
    int e = e0 + ty + 8 * i;
    tile[ty + 8 * i][tx] = W[(size_t)e * EE + f0 + tx] * g[h * EE + e];
  }
  __syncthreads();
  #pragma unroll
  for (int i = 0; i < 4; ++i){
    int f = f0 + ty + 8 * i;
    W1t[((size_t)h * EE + f) * EE + e0 + tx] = f2bf(tile[tx][ty + 8 * i]);
  }
}

// ---------------------------------------------------------------------------
// Wmt[f][c] = bf16( Wm[c][f] )   c in [0,3072), f in [0,768)
// grid (96 c-tiles, 24 f-tiles)
// ---------------------------------------------------------------------------
__global__ __launch_bounds__(256) void k_tWm(const float* __restrict__ Wm,
                                             short* __restrict__ Wmt){
  __shared__ float tile[32][33];
  const int c0 = blockIdx.x * 32, f0 = blockIdx.y * 32;
  const int tx = threadIdx.x & 31, ty = threadIdx.x >> 5;
  #pragma unroll
  for (int i = 0; i < 4; ++i){
    tile[ty + 8 * i][tx] = Wm[(size_t)(c0 + ty + 8 * i) * EE + f0 + tx];
  }
  __syncthreads();
  #pragma unroll
  for (int i = 0; i < 4; ++i){
    Wmt[(size_t)(f0 + ty + 8 * i) * (HH * EE) + c0 + tx] = f2bf(tile[tx][ty + 8 * i]);
  }
}

// ---------------------------------------------------------------------------
// Flash-style fused y pass: ONE WAVE PER ROW n. For each k-row: LN0 ->
// logits d_h = yn . v_h (x_/W2x/b2 cancel in softmax) -> online softmax
// -> acc_h += w * yn. No LDS, no barriers; 2-row register prefetch.
// ---------------------------------------------------------------------------
__global__ __launch_bounds__(256) void k_pass_y(const float* __restrict__ y,
                                                const float* __restrict__ v,
                                                short* __restrict__ p_y){
  const int wave = threadIdx.x >> 6, lane = threadIdx.x & 63;
  const int n = blockIdx.x * 4 + wave;
  const float* base = y + (size_t)n * KK * EE + 4 * lane;

  float4v vreg[HH][3];
  #pragma unroll
  for (int h = 0; h < HH; ++h)
    #pragma unroll
    for (int j = 0; j < 3; ++j)
      vreg[h][j] = *(const float4v*)(v + h * EE + 4 * lane + 256 * j);

  float4v acc[HH][3];
  #pragma unroll
  for (int h = 0; h < HH; ++h)
    #pragma unroll
    for (int j = 0; j < 3; ++j)
      acc[h][j] = (float4v){0.f, 0.f, 0.f, 0.f};
  float m[HH], l[HH];
  #pragma unroll
  for (int h = 0; h < HH; ++h){ m[h] = -INFINITY; l[h] = 0.f; }

  float4v bufA[3], bufB[3];
  #pragma unroll
  for (int j = 0; j < 3; ++j) bufA[j] = *(const float4v*)(base + 256 * j);
  #pragma unroll
  for (int j = 0; j < 3; ++j) bufB[j] = *(const float4v*)(base + EE + 256 * j);

  #pragma unroll 2
  for (int k = 0; k < KK; ++k){
    float4v cur[3];
    #pragma unroll
    for (int j = 0; j < 3; ++j) cur[j] = bufA[j];
    #pragma unroll
    for (int j = 0; j < 3; ++j) bufA[j] = bufB[j];
    if (k + 2 < KK){
      const float* rp = base + (size_t)(k + 2) * EE;
      #pragma unroll
      for (int j = 0; j < 3; ++j) bufB[j] = *(const float4v*)(rp + 256 * j);
    }

    float s = 0.f, s2 = 0.f;
    #pragma unroll
    for (int j = 0; j < 3; ++j)
      #pragma unroll
      for (int c = 0; c < 4; ++c){ float t = cur[j][c]; s += t; s2 += t * t; }
    #pragma unroll
    for (int off = 32; off; off >>= 1){
      s  += __shfl_xor(s, off);
      s2 += __shfl_xor(s2, off);
    }
    const float mu = s * (1.f / EE);
    const float rs = rsqrtf(s2 * (1.f / EE) - mu * mu + 1e-5f);

    float d[HH] = {0.f, 0.f, 0.f, 0.f};
    #pragma unroll
    for (int j = 0; j < 3; ++j)
      #pragma unroll
      for (int c = 0; c < 4; ++c){
        float t = (cur[j][c] - mu) * rs;
        cur[j][c] = t;
        d[0] += t * vreg[0][j][c];
        d[1] += t * vreg[1][j][c];
        d[2] += t * vreg[2][j][c];
        d[3] += t * vreg[3][j][c];
      }
    #pragma unroll
    for (int off = 32; off; off >>= 1){
      d[0] += __shfl_xor(d[0], off);
      d[1] += __shfl_xor(d[1], off);
      d[2] += __shfl_xor(d[2], off);
      d[3] += __shfl_xor(d[3], off);
    }

    #pragma unroll
    for (int h = 0; h < HH; ++h){
      if (d[h] > m[h]){
        float sc = __expf(m[h] - d[h]);   // first iter: exp(-inf)=0
        l[h] *= sc;
        #pragma unroll
        for (int j = 0; j < 3; ++j)
          #pragma unroll
          for (int c = 0; c < 4; ++c) acc[h][j][c] *= sc;
        m[h] = d[h];
      }
      float w = __expf(d[h] - m[h]);
      l[h] += w;
      #pragma unroll
      for (int j = 0; j < 3; ++j)
        #pragma unroll
        for (int c = 0; c < 4; ++c) acc[h][j][c] += w * cur[j][c];
    }
  }

  #pragma unroll
  for (int h = 0; h < HH; ++h){
    const float inv = 1.f / l[h];
    #pragma unroll
    for (int j = 0; j < 3; ++j){
      short4v pk;
      #pragma unroll
      for (int c = 0; c < 4; ++c) pk[c] = f2bf(acc[h][j][c] * inv);
      *(short4v*)(p_y + ((size_t)h * BSN + n) * EE + 4 * lane + 256 * j) = pk;
    }
  }
}

// ---------------------------------------------------------------------------
// 128x128-tile bf16 MFMA GEMM (m97 structure): BK=64, 4 waves in 2x2, each
// wave owns a 64x64 quadrant (acc[4][4] of 16x16 frags). Staging via
// global_load_lds width-16 into LINEAR LDS [128][64] (wave-uniform dest base,
// per-lane global src). 2 barriers per K-step.
// A: [M][Kdim] bf16 row-major. Bt: [N][Kdim] bf16 (B transposed).
// MODE 0 (z=head): cat[m][768z+f] = bf16( gelu(x[m][f] + acc + addv[768z+f]) )
// MODE 1 (z=K-chunk, split-K): part[z][m][f] = acc (f32); epilogue separate.
// grid (M/128, N/128, Z)
// ---------------------------------------------------------------------------
template<int MODE>
__global__ __launch_bounds__(256) void k_gemm128(const short* __restrict__ A,
                                                 const short* __restrict__ Bt,
                                                 const float* __restrict__ addv,
                                                 const float* __restrict__ x,
                                                 void* __restrict__ out,
                                                 int Kdim, size_t strideA, size_t strideB,
                                                 int kchunk){
  __shared__ short As[128 * 64];
  __shared__ short Bs[128 * 64];
  const int z = blockIdx.z;
  const short* Ah; const short* Bh; int kbeg, kend;
  if (MODE == 0){ Ah = A + strideA * z; Bh = Bt + strideB * z; kbeg = 0; kend = Kdim; }
  else          { Ah = A; Bh = Bt; kbeg = z * kchunk; kend = kbeg + kchunk; }

  const int tid = threadIdx.x;
  const int wave = tid >> 6, lane = tid & 63;
  const int wr = wave >> 1, wc = wave & 1;       // 2x2 wave grid over the tile
  const int quad = lane >> 4, l16 = lane & 15;
  const int m0 = blockIdx.x * 128, n0 = blockIdx.y * 128;

  // staging geometry: chunk q (0..15) covers 8 rows (1024 B of LDS); wave w
  // issues chunks q = 4w..4w+3. lane covers row 8q+(lane>>3), col (lane&7)*8.
  const int srow = lane >> 3;
  const int scol = (lane & 7) * 8;
  const int q0 = wave * 4;

  float4v acc[4][4];
  #pragma unroll
  for (int t = 0; t < 4; ++t)
    #pragma unroll
    for (int u = 0; u < 4; ++u) acc[t][u] = (float4v){0.f, 0.f, 0.f, 0.f};

  for (int k0 = kbeg; k0 < kend; k0 += 64){
    __syncthreads();   // all waves done reading LDS from previous K-step
    #pragma unroll
    for (int i = 0; i < 4; ++i){
      const int q = q0 + i;
      gload16(Ah + (size_t)(m0 + 8 * q + srow) * Kdim + k0 + scol, &As[q * 512]);
      gload16(Bh + (size_t)(n0 + 8 * q + srow) * Kdim + k0 + scol, &Bs[q * 512]);
    }
    __syncthreads();   // compiler drains vmcnt(0) before barrier -> LDS ready
    #pragma unroll
    for (int kk = 0; kk < 64; kk += 32){
      short8 bfr[4], afr[4];
      #pragma unroll
      for (int u = 0; u < 4; ++u)
        bfr[u] = *(const short8*)(&Bs[(wc * 64 + 16 * u + l16) * 64 + kk + quad * 8]);
      #pragma unroll
      for (int t = 0; t < 4; ++t)
        afr[t] = *(const short8*)(&As[(wr * 64 + 16 * t + l16) * 64 + kk + quad * 8]);
      #pragma unroll
      for (int t = 0; t < 4; ++t)
        #pragma unroll
        for (int u = 0; u < 4; ++u)
          acc[t][u] = __builtin_amdgcn_mfma_f32_16x16x32_bf16(afr[t], bfr[u], acc[t][u], 0, 0, 0);
    }
  }

  if (MODE == 0){
    #pragma unroll
    for (int u = 0; u < 4; ++u){
      const int f = n0 + wc * 64 + 16 * u + l16;
      const float add = addv[768 * z + f];
      #pragma unroll
      for (int t = 0; t < 4; ++t){
        #pragma unroll
        for (int rr = 0; rr < 4; ++rr){
          const int m = m0 + wr * 64 + 16 * t + quad * 4 + rr;
          const float val = acc[t][u][rr] + add;
          const float xf = x[(size_t)m * EE + f];
          ((short*)out)[(size_t)m * (HH * EE) + 768 * z + f] = f2bf(gelu_tanh(xf + val));
        }
      }
    }
  } else {
    float* po = (float*)out + (size_t)z * BSN * EE;
    #pragma unroll
    for (int u = 0; u < 4; ++u){
      const int f = n0 + wc * 64 + 16 * u + l16;
      #pragma unroll
      for (int t = 0; t < 4; ++t){
        #pragma unroll
        for (int rr = 0; rr < 4; ++rr){
          const int m = m0 + wr * 64 + 16 * t + quad * 4 + rr;
          po[(size_t)m * EE + f] = acc[t][u][rr];
        }
      }
    }
  }
}

// ---------------------------------------------------------------------------
// epilogue for split-K GEMM1: out = x + gelu(p0 + p1 + p2 + p3 + bm)
// ---------------------------------------------------------------------------
__global__ __launch_bounds__(256) void k_ep(const float* __restrict__ part,
                                            const float* __restrict__ bm,
                                            const float* __restrict__ x,
                                            float* __restrict__ out){
  const size_t i = ((size_t)blockIdx.x * 256 + threadIdx.x) * 4;
  float4v s0 = *(const float4v*)(part + i);
  float4v s1 = *(const float4v*)(part + (size_t)BSN * EE + i);
  float4v s2 = *(const float4v*)(part + (size_t)2 * BSN * EE + i);
  float4v s3 = *(const float4v*)(part + (size_t)3 * BSN * EE + i);
  float4v xv = *(const float4v*)(x + i);
  float4v bv = *(const float4v*)(bm + (int)(i % EE));
  float4v o;
  #pragma unroll
  for (int c = 0; c < 4; ++c)
    o[c] = xv[c] + gelu_tanh(s0[c] + s1[c] + s2[c] + s3[c] + bv[c]);
  *(float4v*)(out + i) = o;
}

// ---------------------------------------------------------------------------
extern "C" void kernel_launch(void* const* d_in, const int* in_sizes, int n_in,
                              void* d_out, int out_size, void* d_ws, size_t ws_size,
                              hipStream_t stream){
  const float* x    = (const float*)d_in[0];
  const float* y    = (const float*)d_in[1];
  const float* g    = (const float*)d_in[2];
  const float* beta = (const float*)d_in[3];
  const float* W1   = (const float*)d_in[4];
  const float* b1   = (const float*)d_in[5];
  const float* W2y  = (const float*)d_in[7];   // W2x, b2 cancel in softmax
  const float* Wm   = (const float*)d_in[9];
  const float* bm   = (const float*)d_in[10];

  char* ws = (char*)d_ws;
  float* v    = (float*)(ws + 0);              // 4*768 f32
  float* b1p  = (float*)(ws + 12288);          // 4*768 f32
  short* W1t  = (short*)(ws + 24576);          // 4*768*768 bf16 (transposed)
  short* Wmt  = (short*)(ws + 4743168);        // 768*3072 bf16 (transposed)
  short* p_y  = (short*)(ws + 9461760);        // 4*2048*768 bf16
  short* catb = (short*)(ws + 22044672);       // 2048*3072 bf16
  float* part = (float*)(ws + 34627584);       // 4*2048*768 f32 split-K partials
  float* out  = (float*)d_out;

  k_v<<<dim3(768), dim3(256), 0, stream>>>(W1, W2y, g, b1, v, b1p);
  k_b1p_acc<<<dim3(256), dim3(256), 0, stream>>>(W1, beta, b1p);
  k_tW1<<<dim3(24, 24, 4), dim3(256), 0, stream>>>(W1, g, W1t);
  k_tWm<<<dim3(96, 24), dim3(256), 0, stream>>>(Wm, Wmt);
  k_pass_y<<<dim3(512), dim3(256), 0, stream>>>(y, v, p_y);
  k_gemm128<0><<<dim3(16, 6, 4), dim3(256), 0, stream>>>(
      p_y, W1t, b1p, x, (void*)catb, 768, (size_t)2048 * 768, (size_t)768 * 768, 0);
  k_gemm128<1><<<dim3(16, 6, SPLITK), dim3(256), 0, stream>>>(
      catb, Wmt, nullptr, nullptr, (void*)part, 3072, (size_t)0, (size_t)0, 3072 / SPLITK);
  k_ep<<<dim3(1536), dim3(256), 0, stream>>>(part, bm, x, out);
}

// Round 2
// 427.424 us; speedup vs baseline: 1.0415x; 1.0415x over previous
//
#include <hip/hip_runtime.h>
#include <hip/hip_bf16.h>
#include <math.h>

#define EE 768
#define HH 4
#define KK 36
#define BSN 2048

typedef __attribute__((ext_vector_type(8))) short short8;
typedef __attribute__((ext_vector_type(4))) short short4v;
typedef __attribute__((ext_vector_type(4))) float float4v;

__device__ inline short f2bf(float x){
  return __builtin_bit_cast(short, __float2bfloat16(x));
}
__device__ inline float bf2f(short s){
  return __bfloat162float(__builtin_bit_cast(__hip_bfloat16, s));
}
__device__ inline float gelu_tanh(float x){
  // jax.nn.gelu default (approximate=True)
  float t = tanhf(0.79788456080286536f * (x + 0.044715f * x * x * x));
  return 0.5f * x * (1.0f + t);
}

// ---------------------------------------------------------------------------
// v[h][e] = g[h][e] * sum_f W1[h][e][f] * W2y[h][f]    (one wave per (h,e))
// also initializes b1p = b1 (first 12 blocks' worth of threads)
// ---------------------------------------------------------------------------
__global__ __launch_bounds__(256) void k_v(const float* __restrict__ W1,
                                           const float* __restrict__ W2y,
                                           const float* __restrict__ g,
                                           const float* __restrict__ b1,
                                           float* __restrict__ v,
                                           float* __restrict__ b1p){
  const int wid  = blockIdx.x * 4 + (threadIdx.x >> 6);
  const int lane = threadIdx.x & 63;
  const int h = wid / EE, e = wid % EE;
  const float* W  = W1 + ((size_t)h * EE + e) * EE;
  const float* wy = W2y + h * EE;
  float acc = 0.f;
  #pragma unroll
  for (int j = 0; j < 12; ++j){
    int f = lane + 64 * j;
    acc += W[f] * wy[f];
  }
  #pragma unroll
  for (int off = 32; off; off >>= 1) acc += __shfl_xor(acc, off);
  if (lane == 0) v[h * EE + e] = g[h * EE + e] * acc;

  int idx = blockIdx.x * 256 + threadIdx.x;
  if (idx < HH * EE) b1p[idx] = b1[idx];
}

// ---------------------------------------------------------------------------
// b1p[h][f] += sum_e beta[h][e] * W1[h][e][f]   (partial e-chunks + atomics)
// grid: 256 blocks = 4 h * 64 e-chunks of 12
// ---------------------------------------------------------------------------
__global__ __launch_bounds__(256) void k_b1p_acc(const float* __restrict__ W1,
                                                 const float* __restrict__ beta,
                                                 float* __restrict__ b1p){
  const int h   = blockIdx.x >> 6;
  const int ec0 = (blockIdx.x & 63) * 12;
  const float* W  = W1 + (size_t)h * EE * EE;
  const float* bt = beta + h * EE;
  const int f = threadIdx.x;
  float a0 = 0.f, a1 = 0.f, a2 = 0.f;
  #pragma unroll
  for (int e = ec0; e < ec0 + 12; ++e){
    float be = bt[e];
    const float* row = W + (size_t)e * EE;
    a0 += be * row[f];
    a1 += be * row[f + 256];
    a2 += be * row[f + 512];
  }
  atomicAdd(&b1p[h * EE + f],       a0);
  atomicAdd(&b1p[h * EE + f + 256], a1);
  atomicAdd(&b1p[h * EE + f + 512], a2);
}

// ---------------------------------------------------------------------------
// W1t[h][f][e] = bf16( g[h][e] * W1[h][e][f] )   (transposed, bf16)
// grid (24 e-tiles, 24 f-tiles, 4 h), 256 threads
// ---------------------------------------------------------------------------
__global__ __launch_bounds__(256) void k_tW1(const float* __restrict__ W1,
                                             const float* __restrict__ g,
                                             short* __restrict__ W1t){
  __shared__ float tile[32][33];
  const int h  = blockIdx.z;
  const int e0 = blockIdx.x * 32, f0 = blockIdx.y * 32;
  const int tx = threadIdx.x & 31, ty = threadIdx.x >> 5;
  const float* W = W1 + (size_t)h * EE * EE;
  #pragma unroll
  for (int i = 0; i < 4; ++i){
    int e = e0 + ty + 8 * i;
    tile[ty + 8 * i][tx] = W[(size_t)e * EE + f0 + tx] * g[h * EE + e];
  }
  __syncthreads();
  #pragma unroll
  for (int i = 0; i < 4; ++i){
    int f = f0 + ty + 8 * i;
    W1t[((size_t)h * EE + f) * EE + e0 + tx] = f2bf(tile[tx][ty + 8 * i]);
  }
}

// ---------------------------------------------------------------------------
// Wmt[f][c] = bf16( Wm[c][f] )   c in [0,3072), f in [0,768)
// grid (96 c-tiles, 24 f-tiles)
// ---------------------------------------------------------------------------
__global__ __launch_bounds__(256) void k_tWm(const float* __restrict__ Wm,
                                             short* __restrict__ Wmt){
  __shared__ float tile[32][33];
  const int c0 = blockIdx.x * 32, f0 = blockIdx.y * 32;
  const int tx = threadIdx.x & 31, ty = threadIdx.x >> 5;
  #pragma unroll
  for (int i = 0; i < 4; ++i){
    tile[ty + 8 * i][tx] = Wm[(size_t)(c0 + ty + 8 * i) * EE + f0 + tx];
  }
  __syncthreads();
  #pragma unroll
  for (int i = 0; i < 4; ++i){
    Wmt[(size_t)(f0 + ty + 8 * i) * (HH * EE) + c0 + tx] = f2bf(tile[tx][ty + 8 * i]);
  }
}

// ---------------------------------------------------------------------------
// Flash-style fused y pass: ONE WAVE PER ROW n. For each k-row: LN0 ->
// logits d_h = yn . v_h (x_/W2x/b2 cancel in softmax) -> online softmax
// -> acc_h += w * yn. No LDS, no barriers; 2-row register prefetch.
// ---------------------------------------------------------------------------
__global__ __launch_bounds__(256) void k_pass_y(const float* __restrict__ y,
                                                const float* __restrict__ v,
                                                short* __restrict__ p_y){
  const int wave = threadIdx.x >> 6, lane = threadIdx.x & 63;
  const int n = blockIdx.x * 4 + wave;
  const float* base = y + (size_t)n * KK * EE + 4 * lane;

  float4v vreg[HH][3];
  #pragma unroll
  for (int h = 0; h < HH; ++h)
    #pragma unroll
    for (int j = 0; j < 3; ++j)
      vreg[h][j] = *(const float4v*)(v + h * EE + 4 * lane + 256 * j);

  float4v acc[HH][3];
  #pragma unroll
  for (int h = 0; h < HH; ++h)
    #pragma unroll
    for (int j = 0; j < 3; ++j)
      acc[h][j] = (float4v){0.f, 0.f, 0.f, 0.f};
  float m[HH], l[HH];
  #pragma unroll
  for (int h = 0; h < HH; ++h){ m[h] = -INFINITY; l[h] = 0.f; }

  float4v bufA[3], bufB[3];
  #pragma unroll
  for (int j = 0; j < 3; ++j) bufA[j] = *(const float4v*)(base + 256 * j);
  #pragma unroll
  for (int j = 0; j < 3; ++j) bufB[j] = *(const float4v*)(base + EE + 256 * j);

  #pragma unroll 2
  for (int k = 0; k < KK; ++k){
    float4v cur[3];
    #pragma unroll
    for (int j = 0; j < 3; ++j) cur[j] = bufA[j];
    #pragma unroll
    for (int j = 0; j < 3; ++j) bufA[j] = bufB[j];
    if (k + 2 < KK){
      const float* rp = base + (size_t)(k + 2) * EE;
      #pragma unroll
      for (int j = 0; j < 3; ++j) bufB[j] = *(const float4v*)(rp + 256 * j);
    }

    float s = 0.f, s2 = 0.f;
    #pragma unroll
    for (int j = 0; j < 3; ++j)
      #pragma unroll
      for (int c = 0; c < 4; ++c){ float t = cur[j][c]; s += t; s2 += t * t; }
    #pragma unroll
    for (int off = 32; off; off >>= 1){
      s  += __shfl_xor(s, off);
      s2 += __shfl_xor(s2, off);
    }
    const float mu = s * (1.f / EE);
    const float rs = rsqrtf(s2 * (1.f / EE) - mu * mu + 1e-5f);

    float d[HH] = {0.f, 0.f, 0.f, 0.f};
    #pragma unroll
    for (int j = 0; j < 3; ++j)
      #pragma unroll
      for (int c = 0; c < 4; ++c){
        float t = (cur[j][c] - mu) * rs;
        cur[j][c] = t;
        d[0] += t * vreg[0][j][c];
        d[1] += t * vreg[1][j][c];
        d[2] += t * vreg[2][j][c];
        d[3] += t * vreg[3][j][c];
      }
    #pragma unroll
    for (int off = 32; off; off >>= 1){
      d[0] += __shfl_xor(d[0], off);
      d[1] += __shfl_xor(d[1], off);
      d[2] += __shfl_xor(d[2], off);
      d[3] += __shfl_xor(d[3], off);
    }

    #pragma unroll
    for (int h = 0; h < HH; ++h){
      if (d[h] > m[h]){
        float sc = __expf(m[h] - d[h]);   // first iter: exp(-inf)=0
        l[h] *= sc;
        #pragma unroll
        for (int j = 0; j < 3; ++j)
          #pragma unroll
          for (int c = 0; c < 4; ++c) acc[h][j][c] *= sc;
        m[h] = d[h];
      }
      float w = __expf(d[h] - m[h]);
      l[h] += w;
      #pragma unroll
      for (int j = 0; j < 3; ++j)
        #pragma unroll
        for (int c = 0; c < 4; ++c) acc[h][j][c] += w * cur[j][c];
    }
  }

  #pragma unroll
  for (int h = 0; h < HH; ++h){
    const float inv = 1.f / l[h];
    #pragma unroll
    for (int j = 0; j < 3; ++j){
      short4v pk;
      #pragma unroll
      for (int c = 0; c < 4; ++c) pk[c] = f2bf(acc[h][j][c] * inv);
      *(short4v*)(p_y + ((size_t)h * BSN + n) * EE + 4 * lane + 256 * j) = pk;
    }
  }
}

// ---------------------------------------------------------------------------
// 64x64-tile bf16 MFMA GEMM, C = A @ Bt^T with fused epilogue.
// DOUBLE-BUFFERED: LDS [2][64][72] (padded, conflict-free ds_read_b128),
// register prefetch one K-step ahead, ONE barrier per K-step. Per-step
// critical path = ds_write(next) + 16 MFMA(cur) + barrier; global-load
// latency is hidden under the previous step's MFMA phase.
// A: [M][Kdim] bf16 row-major. Bt: [N][Kdim] bf16 (i.e. B transposed).
// MODE 0 (z=head): cat[m][768z+f] = bf16( gelu(x[m][f] + acc + addv[768z+f]) )
// MODE 1 (z=K-half, split-K): part[z][m][f] = acc (f32); epilogue separate.
// grid (M/64, N/64, Z)
// ---------------------------------------------------------------------------
template<int MODE>
__global__ __launch_bounds__(256) void k_gemm(const short* __restrict__ A,
                                              const short* __restrict__ Bt,
                                              const float* __restrict__ addv,
                                              const float* __restrict__ x,
                                              void* __restrict__ out,
                                              int Kdim, size_t strideA, size_t strideB){
  __shared__ short As[2][64][72];
  __shared__ short Bs[2][64][72];
  const int z = blockIdx.z;
  const short* Ah; const short* Bh; int kbeg, kend;
  if (MODE == 0){ Ah = A + strideA * z; Bh = Bt + strideB * z; kbeg = 0; kend = Kdim; }
  else          { Ah = A; Bh = Bt; kbeg = z * (Kdim >> 1); kend = kbeg + (Kdim >> 1); }

  const int tid = threadIdx.x;
  const int wave = tid >> 6, lane = tid & 63;
  const int quad = lane >> 4, l16 = lane & 15;
  const int m0 = blockIdx.x * 64, n0 = blockIdx.y * 64;
  const int r = tid >> 3, c8 = (tid & 7) * 8;

  float4v acc[4];
  #pragma unroll
  for (int t = 0; t < 4; ++t) acc[t] = (float4v){0.f, 0.f, 0.f, 0.f};

  const short* Ap0 = Ah + (size_t)(m0 + r) * Kdim + c8;
  const short* Ap1 = Ah + (size_t)(m0 + r + 32) * Kdim + c8;
  const short* Bp0 = Bh + (size_t)(n0 + r) * Kdim + c8;
  const short* Bp1 = Bh + (size_t)(n0 + r + 32) * Kdim + c8;

  // prologue: tile 0 -> regs -> LDS buf0; prefetch tile 1 -> regs
  short8 ra0 = *(const short8*)(Ap0 + kbeg);
  short8 ra1 = *(const short8*)(Ap1 + kbeg);
  short8 rb0 = *(const short8*)(Bp0 + kbeg);
  short8 rb1 = *(const short8*)(Bp1 + kbeg);
  *(short8*)(&As[0][r][c8])      = ra0;
  *(short8*)(&As[0][r + 32][c8]) = ra1;
  *(short8*)(&Bs[0][r][c8])      = rb0;
  *(short8*)(&Bs[0][r + 32][c8]) = rb1;
  if (kbeg + 64 < kend){
    ra0 = *(const short8*)(Ap0 + kbeg + 64);
    ra1 = *(const short8*)(Ap1 + kbeg + 64);
    rb0 = *(const short8*)(Bp0 + kbeg + 64);
    rb1 = *(const short8*)(Bp1 + kbeg + 64);
  }
  __syncthreads();

  int cur = 0;
  for (int k0 = kbeg; k0 < kend; k0 += 64){
    if (k0 + 64 < kend){
      const int nx = cur ^ 1;
      // write next tile (regs landed; compiler emits counted vmcnt wait)
      *(short8*)(&As[nx][r][c8])      = ra0;
      *(short8*)(&As[nx][r + 32][c8]) = ra1;
      *(short8*)(&Bs[nx][r][c8])      = rb0;
      *(short8*)(&Bs[nx][r + 32][c8]) = rb1;
      if (k0 + 128 < kend){
        ra0 = *(const short8*)(Ap0 + k0 + 128);
        ra1 = *(const short8*)(Ap1 + k0 + 128);
        rb0 = *(const short8*)(Bp0 + k0 + 128);
        rb1 = *(const short8*)(Bp1 + k0 + 128);
      }
    }
    #pragma unroll
    for (int kk = 0; kk < 64; kk += 32){
      short8 bf = *(const short8*)(&Bs[cur][16 * wave + l16][kk + quad * 8]);
      #pragma unroll
      for (int t = 0; t < 4; ++t){
        short8 af = *(const short8*)(&As[cur][16 * t + l16][kk + quad * 8]);
        acc[t] = __builtin_amdgcn_mfma_f32_16x16x32_bf16(af, bf, acc[t], 0, 0, 0);
      }
    }
    __syncthreads();
    cur ^= 1;
  }

  const int f = n0 + 16 * wave + l16;
  if (MODE == 0){
    const float add = addv[768 * z + f];
    #pragma unroll
    for (int t = 0; t < 4; ++t){
      #pragma unroll
      for (int rr = 0; rr < 4; ++rr){
        const int m = m0 + 16 * t + quad * 4 + rr;
        const float val = acc[t][rr] + add;
        const float xf = x[(size_t)m * EE + f];
        ((short*)out)[(size_t)m * (HH * EE) + 768 * z + f] = f2bf(gelu_tanh(xf + val));
      }
    }
  } else {
    float* po = (float*)out + (size_t)z * BSN * EE;
    #pragma unroll
    for (int t = 0; t < 4; ++t){
      #pragma unroll
      for (int rr = 0; rr < 4; ++rr){
        const int m = m0 + 16 * t + quad * 4 + rr;
        po[(size_t)m * EE + f] = acc[t][rr];
      }
    }
  }
}

// ---------------------------------------------------------------------------
// epilogue for split-K GEMM1: out = x + gelu(p0 + p1 + bm)
// ---------------------------------------------------------------------------
__global__ __launch_bounds__(256) void k_ep(const float* __restrict__ part,
                                            const float* __restrict__ bm,
                                            const float* __restrict__ x,
                                            float* __restrict__ out){
  const size_t i = ((size_t)blockIdx.x * 256 + threadIdx.x) * 4;
  float4v p0 = *(const float4v*)(part + i);
  float4v p1 = *(const float4v*)(part + (size_t)BSN * EE + i);
  float4v xv = *(const float4v*)(x + i);
  float4v bv = *(const float4v*)(bm + (int)(i % EE));
  float4v o;
  #pragma unroll
  for (int c = 0; c < 4; ++c) o[c] = xv[c] + gelu_tanh(p0[c] + p1[c] + bv[c]);
  *(float4v*)(out + i) = o;
}

// ---------------------------------------------------------------------------
extern "C" void kernel_launch(void* const* d_in, const int* in_sizes, int n_in,
                              void* d_out, int out_size, void* d_ws, size_t ws_size,
                              hipStream_t stream){
  const float* x    = (const float*)d_in[0];
  const float* y    = (const float*)d_in[1];
  const float* g    = (const float*)d_in[2];
  const float* beta = (const float*)d_in[3];
  const float* W1   = (const float*)d_in[4];
  const float* b1   = (const float*)d_in[5];
  const float* W2y  = (const float*)d_in[7];   // W2x, b2 cancel in softmax
  const float* Wm   = (const float*)d_in[9];
  const float* bm   = (const float*)d_in[10];

  char* ws = (char*)d_ws;
  float* v    = (float*)(ws + 0);              // 4*768 f32
  float* b1p  = (float*)(ws + 12288);          // 4*768 f32
  short* W1t  = (short*)(ws + 24576);          // 4*768*768 bf16 (transposed)
  short* Wmt  = (short*)(ws + 4743168);        // 768*3072 bf16 (transposed)
  short* p_y  = (short*)(ws + 9461760);        // 4*2048*768 bf16
  short* catb = (short*)(ws + 22044672);       // 2048*3072 bf16
  float* part = (float*)(ws + 34627584);       // 2*2048*768 f32 split-K partials
  float* out  = (float*)d_out;

  k_v<<<dim3(768), dim3(256), 0, stream>>>(W1, W2y, g, b1, v, b1p);
  k_b1p_acc<<<dim3(256), dim3(256), 0, stream>>>(W1, beta, b1p);
  k_tW1<<<dim3(24, 24, 4), dim3(256), 0, stream>>>(W1, g, W1t);
  k_tWm<<<dim3(96, 24), dim3(256), 0, stream>>>(Wm, Wmt);
  k_pass_y<<<dim3(512), dim3(256), 0, stream>>>(y, v, p_y);
  k_gemm<0><<<dim3(32, 12, 4), dim3(256), 0, stream>>>(
      p_y, W1t, b1p, x, (void*)catb, 768, (size_t)2048 * 768, (size_t)768 * 768);
  k_gemm<1><<<dim3(32, 12, 2), dim3(256), 0, stream>>>(
      catb, Wmt, nullptr, nullptr, (void*)part, 3072, (size_t)0, (size_t)0);
  k_ep<<<dim3(1536), dim3(256), 0, stream>>>(part, bm, x, out);
}